// Round 5
// baseline (561.556 us; speedup 1.0000x reference)
//
#include <hip/hip_runtime.h>

#define N_NODES 8192
#define E_EDGES 524288
#define D_DIM   256
#define NEG_FILL -1e9f

#define PROJ_BLOCKS 256
#define ROWS_PER_BLOCK 32

#define NVEC_TOTAL (N_NODES / 4 * N_NODES)   // 16777216 float4s (256 MiB)
#define NVEC_K1    (NVEC_TOTAL / 4)          // 25% filled in K1 (hidden under proj)

#define K1_FILL_BLOCKS  512
#define K2_FILL_BLOCKS  1024
#define K2_SCORE_BLOCKS 1024

typedef float vfloat4 __attribute__((ext_vector_type(4)));
typedef float vfloat2 __attribute__((ext_vector_type(2)));

// K1: blocks [0,256) compute A = h@W1[0:256], B = h@W1[256:512] -> fp8 e4m3 ws
// (4 MiB, L2-resident for K2's gathers); blocks [256,768) fill first 25% of out.
__global__ __launch_bounds__(256) void proj_fill_kernel(
    const float* __restrict__ h,
    const float* __restrict__ W1,
    float* __restrict__ out,
    unsigned char* __restrict__ AB)
{
    if (blockIdx.x < PROJ_BLOCKS) {
        __shared__ float hs[ROWS_PER_BLOCK * D_DIM];   // 32 KB
        const int t  = threadIdx.x;
        const int r0 = blockIdx.x * ROWS_PER_BLOCK;
        const float* hp = h + (long long)r0 * D_DIM;
        for (int i = t; i < ROWS_PER_BLOCK * D_DIM; i += 256) hs[i] = hp[i];
        __syncthreads();

        float accA[ROWS_PER_BLOCK];
        float accB[ROWS_PER_BLOCK];
        #pragma unroll
        for (int r = 0; r < ROWS_PER_BLOCK; ++r) { accA[r] = 0.f; accB[r] = 0.f; }

        for (int k = 0; k < D_DIM; k += 4) {
            float wa0 = W1[(k + 0) * D_DIM + t];
            float wa1 = W1[(k + 1) * D_DIM + t];
            float wa2 = W1[(k + 2) * D_DIM + t];
            float wa3 = W1[(k + 3) * D_DIM + t];
            float wb0 = W1[(256 + k + 0) * D_DIM + t];
            float wb1 = W1[(256 + k + 1) * D_DIM + t];
            float wb2 = W1[(256 + k + 2) * D_DIM + t];
            float wb3 = W1[(256 + k + 3) * D_DIM + t];
            #pragma unroll
            for (int r = 0; r < ROWS_PER_BLOCK; ++r) {
                const float4 hv = *(const float4*)&hs[r * D_DIM + k];
                accA[r] = fmaf(hv.x, wa0, accA[r]);
                accA[r] = fmaf(hv.y, wa1, accA[r]);
                accA[r] = fmaf(hv.z, wa2, accA[r]);
                accA[r] = fmaf(hv.w, wa3, accA[r]);
                accB[r] = fmaf(hv.x, wb0, accB[r]);
                accB[r] = fmaf(hv.y, wb1, accB[r]);
                accB[r] = fmaf(hv.z, wb2, accB[r]);
                accB[r] = fmaf(hv.w, wb3, accB[r]);
            }
        }

        unsigned char* A = AB;
        unsigned char* B = AB + (long long)N_NODES * D_DIM;
        #pragma unroll
        for (int r = 0; r < ROWS_PER_BLOCK; ++r) {
            int pa = __builtin_amdgcn_cvt_pk_fp8_f32(accA[r], accA[r], 0, false);
            int pb = __builtin_amdgcn_cvt_pk_fp8_f32(accB[r], accB[r], 0, false);
            A[(long long)(r0 + r) * D_DIM + t] = (unsigned char)(pa & 0xFF);
            B[(long long)(r0 + r) * D_DIM + t] = (unsigned char)(pb & 0xFF);
        }
    } else {
        const int b = blockIdx.x - PROJ_BLOCKS;
        vfloat4 fv = { NEG_FILL, NEG_FILL, NEG_FILL, NEG_FILL };
        vfloat4* o4 = (vfloat4*)out;
        for (int i = b * 256 + threadIdx.x; i < NVEC_K1; i += K1_FILL_BLOCKS * 256)
            __builtin_nontemporal_store(fv, &o4[i]);
    }
}

// K2: blocks [0,1024) fill the remaining 75% of out (BW-bound, sets kernel
// duration); blocks [1024,2048) compute all edge scores into compact score[]
// (L2-resident fp8 gathers) — overlapped with the fill, no output-line conflict.
__global__ __launch_bounds__(256) void score_fill_kernel(
    const int* __restrict__ eidx,
    const float* __restrict__ eattr,
    const float* __restrict__ W1,
    const float* __restrict__ W2,
    const unsigned char* __restrict__ AB,
    float* __restrict__ score,
    float* __restrict__ out)
{
    if (blockIdx.x < K2_FILL_BLOCKS) {
        const int b = blockIdx.x;
        vfloat4 fv = { NEG_FILL, NEG_FILL, NEG_FILL, NEG_FILL };
        vfloat4* o4 = (vfloat4*)out;
        for (int i = NVEC_K1 + b * 256 + threadIdx.x; i < NVEC_TOTAL; i += K2_FILL_BLOCKS * 256)
            __builtin_nontemporal_store(fv, &o4[i]);
    } else {
        const int w    = (blockIdx.x - K2_FILL_BLOCKS) * 4 + (threadIdx.x >> 6);
        const int lane = threadIdx.x & 63;
        const int j0   = lane * 4;
        const int nw   = K2_SCORE_BLOCKS * 4;           // 4096 waves -> 128 edges each

        const float4 wl  = *(const float4*)&W1[512 * D_DIM + j0];
        const float4 w2v = *(const float4*)&W2[j0];
        const unsigned char* Bt = AB + (long long)N_NODES * D_DIM;
        const int* eR = eidx + E_EDGES;

        int   l_n  = eidx[w];
        int   r_n  = eR[w];
        float at_n = eattr[w];
        for (int e = w; e < E_EDGES; e += nw) {
            const int   l    = l_n;
            const int   r    = r_n;
            const float attr = at_n;
            const int e2 = e + nw;
            if (e2 < E_EDGES) { l_n = eidx[e2]; r_n = eR[e2]; at_n = eattr[e2]; }

            const unsigned int av = *(const unsigned int*)(AB + (long long)l * D_DIM + j0);
            const unsigned int bv = *(const unsigned int*)(Bt + (long long)r * D_DIM + j0);

            vfloat2 a01 = __builtin_amdgcn_cvt_pk_f32_fp8((int)av, false);
            vfloat2 a23 = __builtin_amdgcn_cvt_pk_f32_fp8((int)av, true);
            vfloat2 b01 = __builtin_amdgcn_cvt_pk_f32_fp8((int)bv, false);
            vfloat2 b23 = __builtin_amdgcn_cvt_pk_f32_fp8((int)bv, true);

            float s = 0.f, hv;
            hv = fmaf(attr, wl.x, a01.x + b01.x); hv = fmaxf(hv, 0.f); s = fmaf(hv, w2v.x, s);
            hv = fmaf(attr, wl.y, a01.y + b01.y); hv = fmaxf(hv, 0.f); s = fmaf(hv, w2v.y, s);
            hv = fmaf(attr, wl.z, a23.x + b23.x); hv = fmaxf(hv, 0.f); s = fmaf(hv, w2v.z, s);
            hv = fmaf(attr, wl.w, a23.y + b23.y); hv = fmaxf(hv, 0.f); s = fmaf(hv, w2v.w, s);

            #pragma unroll
            for (int off = 32; off > 0; off >>= 1)
                s += __shfl_xor(s, off, 64);

            if (lane == 0)
                score[e] = s;
        }
    }
}

// K3: thread-per-edge scatter of precomputed scores (coalesced reads,
// byte-masked partial-line writebacks handle cross-XCD same-line stores).
__global__ __launch_bounds__(256) void scatter_kernel(
    const int* __restrict__ eidx,
    const float* __restrict__ score,
    float* __restrict__ out)
{
    const int e = blockIdx.x * 256 + threadIdx.x;
    const int l = eidx[e];
    const int r = eidx[E_EDGES + e];
    out[(long long)l * N_NODES + r] = score[e];
}

extern "C" void kernel_launch(void* const* d_in, const int* in_sizes, int n_in,
                              void* d_out, int out_size, void* d_ws, size_t ws_size,
                              hipStream_t stream) {
    // inputs: 0=encoded (unused), 1=h, 2=edge_index, 3=edge_attr, 4=W1, 5=W2
    const float* h     = (const float*)d_in[1];
    const int*   eidx  = (const int*)d_in[2];
    const float* eattr = (const float*)d_in[3];
    const float* W1    = (const float*)d_in[4];
    const float* W2    = (const float*)d_in[5];
    float* out = (float*)d_out;

    unsigned char* AB    = (unsigned char*)d_ws;              // 4 MiB fp8 A|B
    float*         score = (float*)((char*)d_ws + (4 << 20)); // 2 MiB

    proj_fill_kernel<<<PROJ_BLOCKS + K1_FILL_BLOCKS, 256, 0, stream>>>(h, W1, out, AB);
    score_fill_kernel<<<K2_FILL_BLOCKS + K2_SCORE_BLOCKS, 256, 0, stream>>>(
        eidx, eattr, W1, W2, AB, score, out);
    scatter_kernel<<<E_EDGES / 256, 256, 0, stream>>>(eidx, score, out);
}

// Round 6
// 462.463 us; speedup vs baseline: 1.2143x; 1.2143x over previous
//
#include <hip/hip_runtime.h>

#define N_NODES 8192
#define E_EDGES 524288
#define D_DIM   256
#define NEG_FILL -1e9f

#define PROJ_BLOCKS 256
#define ROWS_PER_BLOCK 32
#define FILL_BLOCKS 1792            // 256 + 1792 = 2048 blocks, one co-resident pass

#define EDGE_BLOCKS 2048
#define EDGES_PER_WAVE 64           // E / (EDGE_BLOCKS * 4 waves)

typedef float vfloat4 __attribute__((ext_vector_type(4)));
typedef float vfloat2 __attribute__((ext_vector_type(2)));

// K1: blocks [0,256) compute A = h@W1[0:256], B = h@W1[256:512] -> fp8 e4m3 ws
// (4 MiB total, L2-resident for K2's gathers); blocks [256,2048) fill ALL of
// out with -1e9 via NT stores. Proj is VALU-bound and hides under the fill.
__global__ __launch_bounds__(256) void fill_proj_kernel(
    const float* __restrict__ h,
    const float* __restrict__ W1,
    float* __restrict__ out,
    unsigned char* __restrict__ AB)
{
    if (blockIdx.x < PROJ_BLOCKS) {
        __shared__ float hs[ROWS_PER_BLOCK * D_DIM];   // 32 KB
        const int t  = threadIdx.x;
        const int r0 = blockIdx.x * ROWS_PER_BLOCK;
        const float* hp = h + (long long)r0 * D_DIM;
        for (int i = t; i < ROWS_PER_BLOCK * D_DIM; i += 256) hs[i] = hp[i];
        __syncthreads();

        float accA[ROWS_PER_BLOCK];
        float accB[ROWS_PER_BLOCK];
        #pragma unroll
        for (int r = 0; r < ROWS_PER_BLOCK; ++r) { accA[r] = 0.f; accB[r] = 0.f; }

        for (int k = 0; k < D_DIM; k += 4) {
            float wa0 = W1[(k + 0) * D_DIM + t];
            float wa1 = W1[(k + 1) * D_DIM + t];
            float wa2 = W1[(k + 2) * D_DIM + t];
            float wa3 = W1[(k + 3) * D_DIM + t];
            float wb0 = W1[(256 + k + 0) * D_DIM + t];
            float wb1 = W1[(256 + k + 1) * D_DIM + t];
            float wb2 = W1[(256 + k + 2) * D_DIM + t];
            float wb3 = W1[(256 + k + 3) * D_DIM + t];
            #pragma unroll
            for (int r = 0; r < ROWS_PER_BLOCK; ++r) {
                const float4 hv = *(const float4*)&hs[r * D_DIM + k];
                accA[r] = fmaf(hv.x, wa0, accA[r]);
                accA[r] = fmaf(hv.y, wa1, accA[r]);
                accA[r] = fmaf(hv.z, wa2, accA[r]);
                accA[r] = fmaf(hv.w, wa3, accA[r]);
                accB[r] = fmaf(hv.x, wb0, accB[r]);
                accB[r] = fmaf(hv.y, wb1, accB[r]);
                accB[r] = fmaf(hv.z, wb2, accB[r]);
                accB[r] = fmaf(hv.w, wb3, accB[r]);
            }
        }

        unsigned char* A = AB;
        unsigned char* B = AB + (long long)N_NODES * D_DIM;
        #pragma unroll
        for (int r = 0; r < ROWS_PER_BLOCK; ++r) {
            int pa = __builtin_amdgcn_cvt_pk_fp8_f32(accA[r], accA[r], 0, false);
            int pb = __builtin_amdgcn_cvt_pk_fp8_f32(accB[r], accB[r], 0, false);
            A[(long long)(r0 + r) * D_DIM + t] = (unsigned char)(pa & 0xFF);
            B[(long long)(r0 + r) * D_DIM + t] = (unsigned char)(pb & 0xFF);
        }
    } else {
        const int b = blockIdx.x - PROJ_BLOCKS;
        const int nvec = (N_NODES / 4) * N_NODES;   // 16777216
        vfloat4 fv = { NEG_FILL, NEG_FILL, NEG_FILL, NEG_FILL };
        vfloat4* o4 = (vfloat4*)out;
        for (int i = b * 256 + threadIdx.x; i < nvec; i += FILL_BLOCKS * 256)
            __builtin_nontemporal_store(fv, &o4[i]);
    }
}

// K2: 2048 blocks x 4 waves; each wave owns 64 consecutive edges.
// Lane-parallel preload of the wave's 64 (l, r, attr) triples (3 coalesced
// loads), per-edge broadcast via __shfl (uniform index -> v_readlane),
// 1-deep software pipeline on the two 256 B fp8 row-gathers.
__global__ __launch_bounds__(256) void edge_kernel(
    const int* __restrict__ eidx,
    const float* __restrict__ eattr,
    const float* __restrict__ W1,
    const float* __restrict__ W2,
    const unsigned char* __restrict__ AB,
    float* __restrict__ out)
{
    const int wave = blockIdx.x * 4 + (threadIdx.x >> 6);
    const int lane = threadIdx.x & 63;
    const int base = wave * EDGES_PER_WAVE;

    // this wave's 64 edges, one per lane
    const int   l_all = eidx[base + lane];
    const int   r_all = eidx[E_EDGES + base + lane];
    const float a_all = eattr[base + lane];

    const int j0 = lane * 4;
    const float4 wl  = *(const float4*)&W1[512 * D_DIM + j0];
    const float4 w2v = *(const float4*)&W2[j0];
    const unsigned char* Bt = AB + (long long)N_NODES * D_DIM;

    // prime the pipeline with edge 0
    int l_c = __shfl(l_all, 0);
    int r_c = __shfl(r_all, 0);
    unsigned int av_c = *(const unsigned int*)(AB + (long long)l_c * D_DIM + j0);
    unsigned int bv_c = *(const unsigned int*)(Bt + (long long)r_c * D_DIM + j0);

    #pragma unroll 4
    for (int i = 0; i < EDGES_PER_WAVE; ++i) {
        const float attr  = __shfl(a_all, i);
        const int   l_cur = l_c;
        const int   r_cur = r_c;
        const unsigned int av = av_c;
        const unsigned int bv = bv_c;
        if (i + 1 < EDGES_PER_WAVE) {            // issue next gathers before compute
            l_c = __shfl(l_all, i + 1);
            r_c = __shfl(r_all, i + 1);
            av_c = *(const unsigned int*)(AB + (long long)l_c * D_DIM + j0);
            bv_c = *(const unsigned int*)(Bt + (long long)r_c * D_DIM + j0);
        }

        vfloat2 a01 = __builtin_amdgcn_cvt_pk_f32_fp8((int)av, false);
        vfloat2 a23 = __builtin_amdgcn_cvt_pk_f32_fp8((int)av, true);
        vfloat2 b01 = __builtin_amdgcn_cvt_pk_f32_fp8((int)bv, false);
        vfloat2 b23 = __builtin_amdgcn_cvt_pk_f32_fp8((int)bv, true);

        float s = 0.f, hv;
        hv = fmaf(attr, wl.x, a01.x + b01.x); hv = fmaxf(hv, 0.f); s = fmaf(hv, w2v.x, s);
        hv = fmaf(attr, wl.y, a01.y + b01.y); hv = fmaxf(hv, 0.f); s = fmaf(hv, w2v.y, s);
        hv = fmaf(attr, wl.z, a23.x + b23.x); hv = fmaxf(hv, 0.f); s = fmaf(hv, w2v.z, s);
        hv = fmaf(attr, wl.w, a23.y + b23.y); hv = fmaxf(hv, 0.f); s = fmaf(hv, w2v.w, s);

        #pragma unroll
        for (int off = 32; off > 0; off >>= 1)
            s += __shfl_xor(s, off, 64);

        if (lane == 0)
            out[(long long)l_cur * N_NODES + r_cur] = s;
    }
}

extern "C" void kernel_launch(void* const* d_in, const int* in_sizes, int n_in,
                              void* d_out, int out_size, void* d_ws, size_t ws_size,
                              hipStream_t stream) {
    // inputs: 0=encoded (unused), 1=h, 2=edge_index, 3=edge_attr, 4=W1, 5=W2
    const float* h     = (const float*)d_in[1];
    const int*   eidx  = (const int*)d_in[2];
    const float* eattr = (const float*)d_in[3];
    const float* W1    = (const float*)d_in[4];
    const float* W2    = (const float*)d_in[5];
    float* out = (float*)d_out;
    unsigned char* AB = (unsigned char*)d_ws;   // 4 MiB (2 * N * D fp8)

    fill_proj_kernel<<<PROJ_BLOCKS + FILL_BLOCKS, 256, 0, stream>>>(h, W1, out, AB);
    edge_kernel<<<EDGE_BLOCKS, 256, 0, stream>>>(eidx, eattr, W1, W2, AB, out);
}